// Round 10
// baseline (383.644 us; speedup 1.0000x reference)
//
#include <hip/hip_runtime.h>
#include <cstdint>
#include <cstddef>

#define M_DIM 4096
#define N_DIM 8192
#define K_DIM 4096

typedef __attribute__((ext_vector_type(4))) int int4v;

// ---------------------------------------------------------------------------
// Pack into MFMA-fragment order (int32 -> int8). R3/R8-verified, identical.
// p = 16-row panel, s = 64-byte kstep, lane l: chunk(p,s) is 1024 B where
// lane l holds row 16p+(l&15), k-bytes s*64 + (l>>4)*16 .. +16.
// ---------------------------------------------------------------------------
__global__ void __launch_bounds__(256) pack_frag(const int* __restrict__ a,
                                                 const int* __restrict__ b,
                                                 unsigned char* __restrict__ pa,
                                                 unsigned char* __restrict__ pb) {
    size_t t = (size_t)blockIdx.x * 256 + threadIdx.x;
    const size_t NA = (size_t)(M_DIM / 16) * (K_DIM / 64) * 64;
    const int* __restrict__ src;
    unsigned char* __restrict__ dst;
    if (t < NA) {
        src = a; dst = pa;
    } else {
        src = b; dst = pb; t -= NA;
    }
    const int l = (int)(t & 63);
    const int s = (int)((t >> 6) & 63);
    const int p = (int)(t >> 12);
    const int* g = src + ((size_t)(16 * p + (l & 15))) * K_DIM + s * 64 + (l >> 4) * 16;
    const int4v* g4 = (const int4v*)g;
    int4v o;
#pragma unroll
    for (int q = 0; q < 4; ++q) {
        int4v v = g4[q];
        o[q] = (v[0] & 0xff) | ((v[1] & 0xff) << 8) | ((v[2] & 0xff) << 16) | (v[3] << 24);
    }
    ((int4v*)dst)[t] = o;
}

// ---------------------------------------------------------------------------
// GEMM: block 256(M) x 256(N), 512 thr = 8 waves (2M x 4N), wave tile
// 128x64, acc[8][4] = 128 AGPR, mfma_i32_16x16x64_i8, BK=64.
// R9 POST-MORTEM: per-tile = LDS(1152) + MFMA(1306) SUM across R3/R6/R9 —
// the per-iter barrier re-syncs all waves, which then storm LDS with
// same-iter af reads while MFMA pipes idle. Full frag dbuf doesn't fit regs
// (R8 spill). FIX: B-fragments load DIRECTLY from packed global to regs
// (bypassing LDS), one full iter ahead:
//   * LDS now A-only: 64 ds_read/CU/tile = 768 cyc < MFMA 1306 -> can't bind.
//   * bf(T) loaded at iter T-1 into regs: no same-iter B dependency; only
//     af's ~150cy ds_read latency remains, covered by the sibling wave.
//   * NO manual vmcnt in the loop: vmcnt retires IN ORDER (m135), and the
//     compiler's counted wait on bf(T) before MFMA(T) — issued at iter T-1
//     AFTER A(T+1)'s DMA — implicitly completes A(T+1) before barrier(T).
//     Raw s_barrier (no drain) once per iter. Prologue: one vmcnt(4).
//   * LDS 3 x 16 KB (A tiles T, T+1, T+2); DMA(T+2) targets o_pre = the
//     buffer read at iter T-1 (reads lgkm-complete before barrier(T-1)).
//   * regs: persistent bf0/bf1 32 + B-ptrs 8 + A-ptrs 4 ~= 50; af transient
//     32 -> peak ~100 arch VGPR < 128 cap. No spill (R8 lesson).
//   * B fetch duplication (2 waves share a panel) absorbed by L1/L2
//     (packed B = 32 MB << 256 MB LLC); FETCH_SIZE should stay ~100 MB.
// ---------------------------------------------------------------------------
__device__ inline void async_copy16(const unsigned char* g, unsigned char* l) {
    __builtin_amdgcn_global_load_lds(
        (const __attribute__((address_space(1))) void*)g,
        (__attribute__((address_space(3))) void*)l,
        16, 0, 0);
}

#define BAR() __builtin_amdgcn_s_barrier()

__global__ void __launch_bounds__(512, 2) gemm_i8(const unsigned char* __restrict__ Ap,
                                                  const unsigned char* __restrict__ Bp,
                                                  const _Float16* __restrict__ arow,
                                                  const _Float16* __restrict__ acol,
                                                  _Float16* __restrict__ Cout) {
    // A-only buffers: tile t at buf (t%3)*16384, panels [0,16K)
    __shared__ __align__(16) unsigned char lds[3 * 16384];

    const int tid  = threadIdx.x;
    const int lane = tid & 63;
    const int wave = tid >> 6;   // 0..7
    const int wr   = wave >> 2;  // 0..1  (M half)
    const int wc   = wave & 3;   // 0..3  (N quarter)
    const int bn   = blockIdx.x; // 0..31 (256 cols)
    const int bm   = blockIdx.y; // 0..15 (256 rows)

    // A staging: wave w stages panels {2w,2w+1}; 2 DMA chunks/tile/wave.
    const unsigned char* aP0 = Ap + (size_t)(bm * 16 + 2 * wave) * 65536 + lane * 16;
    const unsigned char* aP1 = aP0 + 65536;
    const int aL0 = 2 * wave * 1024;
    const int aL1 = aL0 + 1024;

#define STAGE_A(lo)                          \
    do {                                     \
        async_copy16(aP0, lds + (lo) + aL0); \
        async_copy16(aP1, lds + (lo) + aL1); \
        aP0 += 1024; aP1 += 1024;            \
    } while (0)

    // B direct-to-register from packed global: panels bn*16 + wc*4 + {0..3}.
    const unsigned char* bP0 = Bp + (size_t)(bn * 16 + wc * 4) * 65536 + lane * 16;
    const unsigned char* bP1 = bP0 + 65536;
    const unsigned char* bP2 = bP0 + 2 * 65536;
    const unsigned char* bP3 = bP0 + 3 * 65536;

#define LOAD_B(dst)                                                  \
    do {                                                             \
        dst[0] = *(const int4v*)bP0; dst[1] = *(const int4v*)bP1;    \
        dst[2] = *(const int4v*)bP2; dst[3] = *(const int4v*)bP3;    \
        bP0 += 1024; bP1 += 1024; bP2 += 1024; bP3 += 1024;          \
    } while (0)

    const int a_off = wr * 8192 + lane * 16;  // af[i]: + i*1024, i=0..7

    int4v acc[8][4];
#pragma unroll
    for (int i = 0; i < 8; ++i)
#pragma unroll
        for (int j = 0; j < 4; ++j) acc[i][j] = (int4v)0;

    const int NT = K_DIM / 64;  // 64
    const int NU = NT / 2;      // 32

    // prologue: A(0)->buf0, A(1)->buf1; B(0)->bf0
    STAGE_A(0);
    STAGE_A(16384);
    int4v bf0[4], bf1[4];
    LOAD_B(bf0);
    asm volatile("s_waitcnt vmcnt(4)" ::: "memory");  // A(0),A(1) landed; B(0) may fly
    BAR();

    int o_cur = 0, o_nxt = 16384, o_pre = 32768;

#pragma unroll 1
    for (int u = 0; u < NU; ++u) {
        // ===== even iter T=2u: MFMA(af(T), bf0); prefetch B(T+1)->bf1 ======
        {
            if (u < NU - 1) STAGE_A(o_pre);  // A(T+2)
            LOAD_B(bf1);                     // B(T+1), T+1<=63 always
            const unsigned char* Ac = lds + o_cur;
            int4v af[8];
#pragma unroll
            for (int i = 0; i < 8; ++i) af[i] = *(const int4v*)(Ac + a_off + i * 1024);
            asm volatile("" ::: "memory");   // pin loads above; MFMAs interleave up
#pragma unroll
            for (int i = 0; i < 8; ++i)
#pragma unroll
                for (int j = 0; j < 4; ++j)
                    acc[i][j] = __builtin_amdgcn_mfma_i32_16x16x64_i8(af[i], bf0[j],
                                                                      acc[i][j], 0, 0, 0);
            BAR();
            const int t0 = o_cur; o_cur = o_nxt; o_nxt = o_pre; o_pre = t0;
        }
        // ===== odd iter T=2u+1: MFMA(af(T), bf1); prefetch B(T+1)->bf0 =====
        {
            if (u < NU - 1) {
                STAGE_A(o_pre);              // A(T+2)
                LOAD_B(bf0);                 // B(T+1)
            }
            const unsigned char* Ac = lds + o_cur;
            int4v af[8];
#pragma unroll
            for (int i = 0; i < 8; ++i) af[i] = *(const int4v*)(Ac + a_off + i * 1024);
            asm volatile("" ::: "memory");
#pragma unroll
            for (int i = 0; i < 8; ++i)
#pragma unroll
                for (int j = 0; j < 4; ++j)
                    acc[i][j] = __builtin_amdgcn_mfma_i32_16x16x64_i8(af[i], bf1[j],
                                                                      acc[i][j], 0, 0, 0);
            BAR();
            const int t0 = o_cur; o_cur = o_nxt; o_nxt = o_pre; o_pre = t0;
        }
    }
#undef STAGE_A
#undef LOAD_B

    // --- epilogue: C/D layout col=lane&15, row=(lane>>4)*4+reg (verified)
    const int gcol0 = bn * 256 + wc * 64 + (lane & 15);
    float ac4[4];
#pragma unroll
    for (int j = 0; j < 4; ++j) ac4[j] = (float)acol[gcol0 + j * 16];

    const size_t grow0 = (size_t)bm * 256 + wr * 128 + (lane >> 4) * 4;
#pragma unroll
    for (int i = 0; i < 8; ++i) {
#pragma unroll
        for (int r = 0; r < 4; ++r) {
            const size_t row = grow0 + i * 16 + r;
            const float ar = (float)arow[row];
            _Float16* outp = Cout + row * (size_t)N_DIM + gcol0;
#pragma unroll
            for (int j = 0; j < 4; ++j) {
                float v = (float)acc[i][j][r] * ar * ac4[j];
                outp[j * 16] = (_Float16)v;
            }
        }
    }
}

// ---------------------------------------------------------------------------
extern "C" void kernel_launch(void* const* d_in, const int* in_sizes, int n_in,
                              void* d_out, int out_size, void* d_ws, size_t ws_size,
                              hipStream_t stream) {
    const int* a = (const int*)d_in[0];             // [M,K] int32 (int8 values)
    const int* b = (const int*)d_in[1];             // [N,K] int32 (int8 values)
    const _Float16* ar = (const _Float16*)d_in[2];  // [M] fp16
    const _Float16* ac = (const _Float16*)d_in[3];  // [N] fp16
    _Float16* out = (_Float16*)d_out;               // [M,N] fp16

    unsigned char* pa = (unsigned char*)d_ws;        // 16 MB
    unsigned char* pb = pa + (size_t)M_DIM * K_DIM;  // 32 MB

    const size_t total_frag = (size_t)(M_DIM / 16 + N_DIM / 16) * (K_DIM / 64) * 64;
    pack_frag<<<(int)(total_frag / 256), 256, 0, stream>>>(a, b, pa, pb);

    dim3 grid(N_DIM / 256, M_DIM / 256);
    gemm_i8<<<grid, 512, 0, stream>>>(pa, pb, ar, ac, out);
}

// Round 11
// 357.867 us; speedup vs baseline: 1.0720x; 1.0720x over previous
//
#include <hip/hip_runtime.h>
#include <cstdint>
#include <cstddef>

#define M_DIM 4096
#define N_DIM 8192
#define K_DIM 4096

typedef __attribute__((ext_vector_type(4))) int int4v;

// ---------------------------------------------------------------------------
// Pack into MFMA-fragment order (int32 -> int8). R3/R8-verified, identical.
// ---------------------------------------------------------------------------
__global__ void __launch_bounds__(256) pack_frag(const int* __restrict__ a,
                                                 const int* __restrict__ b,
                                                 unsigned char* __restrict__ pa,
                                                 unsigned char* __restrict__ pb) {
    size_t t = (size_t)blockIdx.x * 256 + threadIdx.x;
    const size_t NA = (size_t)(M_DIM / 16) * (K_DIM / 64) * 64;
    const int* __restrict__ src;
    unsigned char* __restrict__ dst;
    if (t < NA) {
        src = a; dst = pa;
    } else {
        src = b; dst = pb; t -= NA;
    }
    const int l = (int)(t & 63);
    const int s = (int)((t >> 6) & 63);
    const int p = (int)(t >> 12);
    const int* g = src + ((size_t)(16 * p + (l & 15))) * K_DIM + s * 64 + (l >> 4) * 16;
    const int4v* g4 = (const int4v*)g;
    int4v o;
#pragma unroll
    for (int q = 0; q < 4; ++q) {
        int4v v = g4[q];
        o[q] = (v[0] & 0xff) | ((v[1] & 0xff) << 8) | ((v[2] & 0xff) << 16) | (v[3] << 24);
    }
    ((int4v*)dst)[t] = o;
}

// ---------------------------------------------------------------------------
// GEMM: block 256(M) x 256(N), 512 thr = 8 waves (2M x 4N), wave tile
// 128x64, acc[8][4] = 128 AGPR, mfma_i32_16x16x64_i8, BK=64.
// R3/R6/R9/R10 LAW: per-tile time = LDS + MFMA SUM in every barrier-locked
// structure (ratios 0.89-1.00). Cause: MFMA blocks its wave (no async MFMA
// on CDNA4) -> a wave can never overlap its own reads with its own MFMAs;
// overlap requires the SIBLING wave on the SIMD to be in the OPPOSITE
// phase, and a common barrier point forces both into the SAME phase.
// R11 FIX: SPLIT-BARRIER ANTI-PHASE GROUPS. Waves 0-3 (A) and 4-7 (B) hit
// the same one-barrier-per-iter at different program points:
//   A: { stage(T+2); read(T); MFMA(T);            vmcnt; BAR }
//   B: { MFMA(T-1);  stage(T+2); read(T);         vmcnt; BAR }
// At each rendezvous A just computed, B just read. Post-barrier, A reads
// T+1 WHILE B computes T, then they swap. With wave i -> SIMD i%4, each
// SIMD hosts one A-wave + one B-wave: MFMA pipe and LDS pipe both stay fed
// by construction. B carries its 48 frag VGPRs across one barrier: live
// set ~75 arch VGPR << 128 cap (no R8 spill). Ledger = R9's (verified):
// 3 x 32KB buffers, DMA 2-ahead, boundary vmcnt(4) counted (tile T+1
// completes, T+2 in flight), tail drains to 0. B does its last MFMA
// (tile 63) after the loop. First iter: B skips MFMA (uniform guard).
// Buffer reuse: DMA(T+2) at iter T targets buf((T+2)%3) = buf of tile
// T-1, whose last readers (A and B both read T-1 during iter T-1) are
// lgkm-complete before their consuming MFMAs, hence before barrier(T-1),
// which precedes this issue. Race-free.
// ---------------------------------------------------------------------------
__device__ inline void async_copy16(const unsigned char* g, unsigned char* l) {
    __builtin_amdgcn_global_load_lds(
        (const __attribute__((address_space(1))) void*)g,
        (__attribute__((address_space(3))) void*)l,
        16, 0, 0);
}

#define BAR() __builtin_amdgcn_s_barrier()

__global__ void __launch_bounds__(512, 2) gemm_i8(const unsigned char* __restrict__ Ap,
                                                  const unsigned char* __restrict__ Bp,
                                                  const _Float16* __restrict__ arow,
                                                  const _Float16* __restrict__ acol,
                                                  _Float16* __restrict__ Cout) {
    // buffer for tile t at (t%3)*32768: A panels [0,16K), B panels [16K,32K)
    __shared__ __align__(16) unsigned char lds[3 * 32768];

    const int tid  = threadIdx.x;
    const int lane = tid & 63;
    const int wave = tid >> 6;       // 0..7
    const int wr   = wave >> 2;      // 0..1 (M half) — ALSO the phase group
    const int wc   = wave & 3;       // 0..3 (N quarter)
    const bool isB = (wr == 1);      // group B: waves 4..7 (SIMD i%4 pairs A+B)
    const int bn   = blockIdx.x;     // 0..31 (256 cols)
    const int bm   = blockIdx.y;     // 0..15 (256 rows)

    // staging: wave w stages A panels {2w,2w+1} and B panels {2w,2w+1};
    // 4 chunks = 4 KB per wave per K-tile (32 KB per tile per block).
    const unsigned char* aP0 = Ap + (size_t)(bm * 16 + 2 * wave) * 65536 + lane * 16;
    const unsigned char* aP1 = aP0 + 65536;
    const unsigned char* bP0 = Bp + (size_t)(bn * 16 + 2 * wave) * 65536 + lane * 16;
    const unsigned char* bP1 = bP0 + 65536;
    const int aL0 = 2 * wave * 1024, aL1 = aL0 + 1024;
    const int bL0 = 16384 + 2 * wave * 1024, bL1 = bL0 + 1024;

#define STAGE(lo)                                  \
    do {                                           \
        async_copy16(aP0, lds + (lo) + aL0);       \
        async_copy16(aP1, lds + (lo) + aL1);       \
        async_copy16(bP0, lds + (lo) + bL0);       \
        async_copy16(bP1, lds + (lo) + bL1);       \
        aP0 += 1024; aP1 += 1024;                  \
        bP0 += 1024; bP1 += 1024;                  \
    } while (0)

    const int a_off = wr * 8192 + lane * 16;          // af[i]: + i*1024, i=0..7
    const int b_off = 16384 + wc * 4096 + lane * 16;  // bf[j]: + j*1024, j=0..3

    int4v acc[8][4];
#pragma unroll
    for (int i = 0; i < 8; ++i)
#pragma unroll
        for (int j = 0; j < 4; ++j) acc[i][j] = (int4v)0;

    const int NT = K_DIM / 64;  // 64

    // prologue: stage tiles 0,1 into buffers 0,1
    STAGE(0);
    STAGE(32768);
    asm volatile("s_waitcnt vmcnt(4)" ::: "memory");  // tile 0 landed, 1 in flight
    BAR();

    int4v af[8], bf[4];

#define MFMA_CLUSTER()                                                          \
    do {                                                                        \
        _Pragma("unroll")                                                       \
        for (int i = 0; i < 8; ++i)                                             \
            _Pragma("unroll")                                                   \
            for (int j = 0; j < 4; ++j)                                         \
                acc[i][j] = __builtin_amdgcn_mfma_i32_16x16x64_i8(af[i], bf[j], \
                                                                  acc[i][j], 0, 0, 0); \
    } while (0)

#pragma unroll 1
    for (int T = 0; T < NT; ++T) {
        // group B computes tile T-1 from regs carried across the barrier —
        // runs WHILE group A (post-barrier) is doing its tile-T ds_reads.
        if (isB && T > 0) MFMA_CLUSTER();

        if (T + 2 < NT) STAGE(((T + 2) % 3) * 32768);

        // read tile T fragments (resident per ledger)
        const unsigned char* Ac = lds + (T % 3) * 32768;
#pragma unroll
        for (int i = 0; i < 8; ++i) af[i] = *(const int4v*)(Ac + a_off + i * 1024);
#pragma unroll
        for (int j = 0; j < 4; ++j) bf[j] = *(const int4v*)(Ac + b_off + j * 1024);

        // group A computes tile T now — group B's tile-T MFMAs run next
        // iter, overlapping A's tile-T+1 reads.
        if (!isB) MFMA_CLUSTER();

        if (T + 2 < NT) {
            asm volatile("s_waitcnt vmcnt(4)" ::: "memory");  // T+1 done, T+2 in flight
        } else {
            asm volatile("s_waitcnt vmcnt(0)" ::: "memory");
        }
        BAR();
    }
    // group B's final tile
    if (isB) MFMA_CLUSTER();
#undef STAGE
#undef MFMA_CLUSTER

    // --- epilogue: C/D layout col=lane&15, row=(lane>>4)*4+reg (verified)
    const int gcol0 = bn * 256 + wc * 64 + (lane & 15);
    float ac4[4];
#pragma unroll
    for (int j = 0; j < 4; ++j) ac4[j] = (float)acol[gcol0 + j * 16];

    const size_t grow0 = (size_t)bm * 256 + wr * 128 + (lane >> 4) * 4;
#pragma unroll
    for (int i = 0; i < 8; ++i) {
#pragma unroll
        for (int r = 0; r < 4; ++r) {
            const size_t row = grow0 + i * 16 + r;
            const float ar = (float)arow[row];
            _Float16* outp = Cout + row * (size_t)N_DIM + gcol0;
#pragma unroll
            for (int j = 0; j < 4; ++j) {
                float v = (float)acc[i][j][r] * ar * ac4[j];
                outp[j * 16] = (_Float16)v;
            }
        }
    }
}

// ---------------------------------------------------------------------------
extern "C" void kernel_launch(void* const* d_in, const int* in_sizes, int n_in,
                              void* d_out, int out_size, void* d_ws, size_t ws_size,
                              hipStream_t stream) {
    const int* a = (const int*)d_in[0];             // [M,K] int32 (int8 values)
    const int* b = (const int*)d_in[1];             // [N,K] int32 (int8 values)
    const _Float16* ar = (const _Float16*)d_in[2];  // [M] fp16
    const _Float16* ac = (const _Float16*)d_in[3];  // [N] fp16
    _Float16* out = (_Float16*)d_out;               // [M,N] fp16

    unsigned char* pa = (unsigned char*)d_ws;        // 16 MB
    unsigned char* pb = pa + (size_t)M_DIM * K_DIM;  // 32 MB

    const size_t total_frag = (size_t)(M_DIM / 16 + N_DIM / 16) * (K_DIM / 64) * 64;
    pack_frag<<<(int)(total_frag / 256), 256, 0, stream>>>(a, b, pa, pb);

    dim3 grid(N_DIM / 256, M_DIM / 256);
    gemm_i8<<<grid, 512, 0, stream>>>(pa, pb, ar, ac, out);
}